// Round 1
// baseline (1644.032 us; speedup 1.0000x reference)
//
#include <hip/hip_runtime.h>

#define NT 256
#define TILE 32

__device__ __forceinline__ float lrelu(float x, float s) { return x >= 0.0f ? x : s * x; }

// Per-layer node init:
//   h    = lrelu(node_emb[nid+1] @ exp_W + exp_b, 0.1)
//   extra= emb_cat[cat] + lrelu(feat @ proj_W + proj_b, 0.01)
//   mix  = lrelu(lrelu(extra @ dW1 + db1, 0.1) @ dW2 + db2, 0.1)
//   out  = h + mix
// Block: 256 threads, TILE=32 nodes. Thread tile: 4 f x 4 n.
// Activations staged transposed s_x[k][n] so the hot k-loop reads are
// float4 + broadcast (conflict-free); LDS writes are cold paths.
__global__ __launch_bounds__(NT)
void init_layer_kernel(const int* __restrict__ nid, const int* __restrict__ cat,
                       const float* __restrict__ feat,
                       const float* __restrict__ node_emb,
                       const float* __restrict__ exp_W, const float* __restrict__ exp_b,
                       const float* __restrict__ emb_cat,
                       const float* __restrict__ proj_W, const float* __restrict__ proj_b,
                       const float* __restrict__ dW1, const float* __restrict__ db1,
                       const float* __restrict__ dW2, const float* __restrict__ db2,
                       float* __restrict__ out)
{
    __shared__ float s_in[32][TILE];
    __shared__ float s_ft[32][TILE];
    __shared__ float s_x[128][TILE];

    const int t = threadIdx.x;
    const int base = blockIdx.x * TILE;
    const int fg = t & 31, ng = t >> 5;
    const int f0 = fg * 4, n0 = ng * 4;

    // Stage emb + feat rows, transposed [k][n]. Global reads coalesced per row.
    for (int idx = t; idx < TILE * 32; idx += NT) {
        const int n = idx >> 5, k = idx & 31;
        const int g = nid[base + n] + 1;
        s_in[k][n] = node_emb[g * 32 + k];
        s_ft[k][n] = feat[(base + n) * 32 + k];
    }
    __syncthreads();

    // Phase A: two 32->128 matvecs (h and proj)
    float acch[4][4], accp[4][4];
    #pragma unroll
    for (int j = 0; j < 4; ++j)
        #pragma unroll
        for (int i = 0; i < 4; ++i) { acch[j][i] = 0.f; accp[j][i] = 0.f; }

    for (int k = 0; k < 32; ++k) {
        const float4 wev = *reinterpret_cast<const float4*>(&exp_W[k * 128 + f0]);
        const float4 wpv = *reinterpret_cast<const float4*>(&proj_W[k * 128 + f0]);
        const float4 xev = *reinterpret_cast<const float4*>(&s_in[k][n0]);
        const float4 xfv = *reinterpret_cast<const float4*>(&s_ft[k][n0]);
        const float we[4] = {wev.x, wev.y, wev.z, wev.w};
        const float wp[4] = {wpv.x, wpv.y, wpv.z, wpv.w};
        const float xe[4] = {xev.x, xev.y, xev.z, xev.w};
        const float xf[4] = {xfv.x, xfv.y, xfv.z, xfv.w};
        #pragma unroll
        for (int j = 0; j < 4; ++j)
            #pragma unroll
            for (int i = 0; i < 4; ++i) {
                acch[j][i] += xe[j] * we[i];
                accp[j][i] += xf[j] * wp[i];
            }
    }

    // extra = emb_cat[cat] + lrelu(p, 0.01) -> stage transposed
    #pragma unroll
    for (int j = 0; j < 4; ++j) {
        const int cidx = cat[base + n0 + j];
        const float4 ecv = *reinterpret_cast<const float4*>(&emb_cat[cidx * 128 + f0]);
        const float ec[4] = {ecv.x, ecv.y, ecv.z, ecv.w};
        #pragma unroll
        for (int i = 0; i < 4; ++i) {
            const float p = lrelu(accp[j][i] + proj_b[f0 + i], 0.01f);
            s_x[f0 + i][n0 + j] = ec[i] + p;
        }
    }
    #pragma unroll
    for (int j = 0; j < 4; ++j)
        #pragma unroll
        for (int i = 0; i < 4; ++i)
            acch[j][i] = lrelu(acch[j][i] + exp_b[f0 + i], 0.1f);
    __syncthreads();

    // Phase B: t = lrelu(extra @ dW1 + db1, 0.1)
    float acc[4][4];
    #pragma unroll
    for (int j = 0; j < 4; ++j)
        #pragma unroll
        for (int i = 0; i < 4; ++i) acc[j][i] = 0.f;
    for (int k = 0; k < 128; ++k) {
        const float4 wv = *reinterpret_cast<const float4*>(&dW1[k * 128 + f0]);
        const float4 xv = *reinterpret_cast<const float4*>(&s_x[k][n0]);
        const float w[4] = {wv.x, wv.y, wv.z, wv.w};
        const float x[4] = {xv.x, xv.y, xv.z, xv.w};
        #pragma unroll
        for (int j = 0; j < 4; ++j)
            #pragma unroll
            for (int i = 0; i < 4; ++i)
                acc[j][i] += x[j] * w[i];
    }
    __syncthreads();
    #pragma unroll
    for (int j = 0; j < 4; ++j)
        #pragma unroll
        for (int i = 0; i < 4; ++i)
            s_x[f0 + i][n0 + j] = lrelu(acc[j][i] + db1[f0 + i], 0.1f);
    __syncthreads();

    // Phase C: mix = lrelu(t @ dW2 + db2, 0.1); out = h + mix
    #pragma unroll
    for (int j = 0; j < 4; ++j)
        #pragma unroll
        for (int i = 0; i < 4; ++i) acc[j][i] = 0.f;
    for (int k = 0; k < 128; ++k) {
        const float4 wv = *reinterpret_cast<const float4*>(&dW2[k * 128 + f0]);
        const float4 xv = *reinterpret_cast<const float4*>(&s_x[k][n0]);
        const float w[4] = {wv.x, wv.y, wv.z, wv.w};
        const float x[4] = {xv.x, xv.y, xv.z, xv.w};
        #pragma unroll
        for (int j = 0; j < 4; ++j)
            #pragma unroll
            for (int i = 0; i < 4; ++i)
                acc[j][i] += x[j] * w[i];
    }
    #pragma unroll
    for (int j = 0; j < 4; ++j) {
        float4 o;
        float v[4];
        #pragma unroll
        for (int i = 0; i < 4; ++i)
            v[i] = acch[j][i] + lrelu(acc[j][i] + db2[f0 + i], 0.1f);
        o.x = v[0]; o.y = v[1]; o.z = v[2]; o.w = v[3];
        *reinterpret_cast<float4*>(&out[(base + n0 + j) * 128 + f0]) = o;
    }
}

// GraphSAGE block: mean over exactly FAN=10 in-edges (dst = e/10 by
// construction), concat [h_self, mean], 256->128 matvec + lrelu, 128->128
// matvec (+bias), then lrelu or row-L2-normalize (last block).
__global__ __launch_bounds__(NT)
void conv_kernel(const float* __restrict__ h_src, float* __restrict__ h_dst,
                 const int* __restrict__ src,
                 const float* __restrict__ W1, const float* __restrict__ b1,
                 const float* __restrict__ W2, const float* __restrict__ b2,
                 int do_norm)
{
    __shared__ float s_x[256][TILE];
    __shared__ float s_inv[TILE];

    const int t = threadIdx.x;
    const int base = blockIdx.x * TILE;
    const int fg = t & 31, ng = t >> 5;
    const int f0 = fg * 4, n0 = ng * 4;
    const int f = t & 127, half = t >> 7;

    // Stage h_self and gather-mean, transposed [k][n]
    for (int j = 0; j < 16; ++j) {
        const int n = half * 16 + j;
        const int row = base + n;
        s_x[f][n] = h_dst[row * 128 + f];
        float m = 0.f;
        const int* sp = &src[row * 10];
        #pragma unroll
        for (int e = 0; e < 10; ++e)
            m += h_src[sp[e] * 128 + f];
        s_x[128 + f][n] = m * 0.1f;
    }
    __syncthreads();

    // matvec1: k < 256
    float acc[4][4];
    #pragma unroll
    for (int j = 0; j < 4; ++j)
        #pragma unroll
        for (int i = 0; i < 4; ++i) acc[j][i] = 0.f;
    for (int k = 0; k < 256; ++k) {
        const float4 wv = *reinterpret_cast<const float4*>(&W1[k * 128 + f0]);
        const float4 xv = *reinterpret_cast<const float4*>(&s_x[k][n0]);
        const float w[4] = {wv.x, wv.y, wv.z, wv.w};
        const float x[4] = {xv.x, xv.y, xv.z, xv.w};
        #pragma unroll
        for (int j = 0; j < 4; ++j)
            #pragma unroll
            for (int i = 0; i < 4; ++i)
                acc[j][i] += x[j] * w[i];
    }
    __syncthreads();
    #pragma unroll
    for (int j = 0; j < 4; ++j)
        #pragma unroll
        for (int i = 0; i < 4; ++i)
            s_x[f0 + i][n0 + j] = lrelu(acc[j][i] + b1[f0 + i], 0.1f);
    __syncthreads();

    // matvec2: k < 128
    #pragma unroll
    for (int j = 0; j < 4; ++j)
        #pragma unroll
        for (int i = 0; i < 4; ++i) acc[j][i] = 0.f;
    for (int k = 0; k < 128; ++k) {
        const float4 wv = *reinterpret_cast<const float4*>(&W2[k * 128 + f0]);
        const float4 xv = *reinterpret_cast<const float4*>(&s_x[k][n0]);
        const float w[4] = {wv.x, wv.y, wv.z, wv.w};
        const float x[4] = {xv.x, xv.y, xv.z, xv.w};
        #pragma unroll
        for (int j = 0; j < 4; ++j)
            #pragma unroll
            for (int i = 0; i < 4; ++i)
                acc[j][i] += x[j] * w[i];
    }
    float hn[4][4];
    #pragma unroll
    for (int j = 0; j < 4; ++j)
        #pragma unroll
        for (int i = 0; i < 4; ++i)
            hn[j][i] = acc[j][i] + b2[f0 + i];

    if (do_norm) {
        __syncthreads();
        #pragma unroll
        for (int j = 0; j < 4; ++j)
            #pragma unroll
            for (int i = 0; i < 4; ++i)
                s_x[f0 + i][n0 + j] = hn[j][i];
        __syncthreads();
        if (t < TILE) {
            float ss = 0.f;
            for (int k = 0; k < 128; ++k) {
                const float v = s_x[k][t];
                ss += v * v;
            }
            s_inv[t] = 1.0f / fmaxf(sqrtf(ss), 1e-6f);
        }
        __syncthreads();
        #pragma unroll
        for (int j = 0; j < 4; ++j) {
            const float sc = s_inv[n0 + j];
            float4 o;
            o.x = hn[j][0] * sc; o.y = hn[j][1] * sc;
            o.z = hn[j][2] * sc; o.w = hn[j][3] * sc;
            *reinterpret_cast<float4*>(&h_dst[(base + n0 + j) * 128 + f0]) = o;
        }
    } else {
        #pragma unroll
        for (int j = 0; j < 4; ++j) {
            float4 o;
            o.x = lrelu(hn[j][0], 0.1f); o.y = lrelu(hn[j][1], 0.1f);
            o.z = lrelu(hn[j][2], 0.1f); o.w = lrelu(hn[j][3], 0.1f);
            *reinterpret_cast<float4*>(&h_dst[(base + n0 + j) * 128 + f0]) = o;
        }
    }
}

extern "C" void kernel_launch(void* const* d_in, const int* in_sizes, int n_in,
                              void* d_out, int out_size, void* d_ws, size_t ws_size,
                              hipStream_t stream)
{
    // setup_inputs() dict order:
    // 0:nid0 1:cat0 2:feat0 3:nid1 4:cat1 5:feat1 6:nid2 7:cat2 8:feat2
    // 9:nid3 10:cat3 11:feat3 12:src0 13:dst0 14:src1 15:dst1 16:src2 17:dst2
    // 18:node_emb 19:exp_W 20:exp_b 21:emb_cat 22:proj_W 23:proj_b
    // 24:d_W1 25:d_b1 26:d_W2 27:d_b2 28:conv_W1 29:conv_b1 30:conv_W2 31:conv_b2
    const int* nid[4]  = {(const int*)d_in[0], (const int*)d_in[3], (const int*)d_in[6], (const int*)d_in[9]};
    const int* cat[4]  = {(const int*)d_in[1], (const int*)d_in[4], (const int*)d_in[7], (const int*)d_in[10]};
    const float* feat[4] = {(const float*)d_in[2], (const float*)d_in[5], (const float*)d_in[8], (const float*)d_in[11]};
    const int* src[3]  = {(const int*)d_in[12], (const int*)d_in[14], (const int*)d_in[16]};
    const float* node_emb = (const float*)d_in[18];
    const float* exp_W  = (const float*)d_in[19];
    const float* exp_b  = (const float*)d_in[20];
    const float* emb_cat = (const float*)d_in[21];
    const float* proj_W = (const float*)d_in[22];
    const float* proj_b = (const float*)d_in[23];
    const float* dW1    = (const float*)d_in[24];
    const float* db1    = (const float*)d_in[25];
    const float* dW2    = (const float*)d_in[26];
    const float* db2    = (const float*)d_in[27];
    const float* cW1    = (const float*)d_in[28];
    const float* cb1    = (const float*)d_in[29];
    const float* cW2    = (const float*)d_in[30];
    const float* cb2    = (const float*)d_in[31];

    const int L[4] = {524288, 131072, 32768, 8192};
    float* hs[4];
    hs[0] = (float*)d_ws;
    hs[1] = hs[0] + (size_t)L[0] * 128;
    hs[2] = hs[1] + (size_t)L[1] * 128;
    hs[3] = (float*)d_out;

    for (int i = 0; i < 4; ++i) {
        init_layer_kernel<<<L[i] / TILE, NT, 0, stream>>>(
            nid[i], cat[i], feat[i], node_emb, exp_W, exp_b, emb_cat,
            proj_W, proj_b, dW1, db1, dW2, db2, hs[i]);
    }
    for (int b = 0; b < 3; ++b) {
        conv_kernel<<<L[b + 1] / TILE, NT, 0, stream>>>(
            hs[b], hs[b + 1], src[b],
            cW1 + (size_t)b * 256 * 128, cb1 + (size_t)b * 128,
            cW2 + (size_t)b * 128 * 128, cb2 + (size_t)b * 128,
            b == 2 ? 1 : 0);
    }
}

// Round 2
// 735.964 us; speedup vs baseline: 2.2338x; 2.2338x over previous
//
#include <hip/hip_runtime.h>

// ---------------------------------------------------------------------------
// GraphSAGE forward, bf16-MFMA version.
// MFMA 16x16x32 bf16 layout assumptions (gfx950, per guide §3):
//   A (arg0): lane l holds A[l&15][(l>>4)*8 + j], j=0..7   (M=16 rows, K=32)
//   B (arg1): lane l holds B[(l>>4)*8 + j][l&15]           (K=32, N=16 cols)
//   C/D     : lane l, reg r holds D[(l>>4)*4 + r][l&15]    (verified m89/m91)
// Note: any permutation error in the per-lane k-map cancels (A and B use the
// same map); only the lane&15 row/col convention affects correctness.
// ---------------------------------------------------------------------------

typedef __attribute__((ext_vector_type(8))) short short8;
typedef __attribute__((ext_vector_type(4))) float f32x4;

__device__ __forceinline__ float lrelu(float x, float s) { return x >= 0.0f ? x : s * x; }

// f32 -> bf16 round-to-nearest-even
__device__ __forceinline__ unsigned short f2bf(float x) {
    unsigned u = __float_as_uint(x);
    unsigned r = (u + 0x7FFFu + ((u >> 16) & 1u)) >> 16;
    return (unsigned short)r;
}
__device__ __forceinline__ float bf2f(unsigned short u) {
    return __uint_as_float(((unsigned)u) << 16);
}

// --- weight pre-permute: f32 [K][128] -> bf16 fragment order --------------
// dest elem = base + ((kc*8 + ft)*64 + lane)*8 + j
//   kc=k>>5, kr=k&31, ft=f>>4, lane=((kr>>3)<<4)|(f&15), j=kr&7
#define W_EXP   0
#define W_PROJ  4096
#define W_D1    8192
#define W_D2    24576
#define W_C1    40960      // + b*32768
#define W_C2    139264     // + b*16384
#define W_TOTAL 188416

__global__ __launch_bounds__(256)
void prep_weights(const float* __restrict__ expW, const float* __restrict__ projW,
                  const float* __restrict__ dW1, const float* __restrict__ dW2,
                  const float* __restrict__ cW1, const float* __restrict__ cW2,
                  unsigned short* __restrict__ dst)
{
    int gid = blockIdx.x * 256 + threadIdx.x;
    if (gid >= W_TOTAL) return;
    const float* src; int e, dbase;
    if (gid < W_PROJ)      { src = expW;  e = gid;          dbase = W_EXP; }
    else if (gid < W_D1)   { src = projW; e = gid - W_PROJ; dbase = W_PROJ; }
    else if (gid < W_D2)   { src = dW1;   e = gid - W_D1;   dbase = W_D1; }
    else if (gid < W_C1)   { src = dW2;   e = gid - W_D2;   dbase = W_D2; }
    else if (gid < W_C2)   { int r = gid - W_C1; int b = r / 32768; int w = r % 32768;
                             src = cW1 + (size_t)b * 32768; e = w; dbase = W_C1 + b * 32768; }
    else                   { int r = gid - W_C2; int b = r / 16384; int w = r % 16384;
                             src = cW2 + (size_t)b * 16384; e = w; dbase = W_C2 + b * 16384; }
    int k = e >> 7, f = e & 127;
    int kc = k >> 5, kr = k & 31, ft = f >> 4;
    int lane = ((kr >> 3) << 4) | (f & 15);
    int j = kr & 7;
    dst[dbase + ((kc * 8 + ft) * 64 + lane) * 8 + j] = f2bf(src[e]);
}

// --- per-layer node init ---------------------------------------------------
// 64 nodes per block, 4 waves, wave w owns nodes [w*16, w*16+16).
__global__ __launch_bounds__(256, 4)
void init_layer(const int* __restrict__ nid, const int* __restrict__ cat,
                const float* __restrict__ feat,
                const float* __restrict__ node_emb,
                const unsigned short* __restrict__ wExp, const float* __restrict__ exp_b,
                const float* __restrict__ emb_cat,
                const unsigned short* __restrict__ wProj, const float* __restrict__ proj_b,
                const unsigned short* __restrict__ wD1, const float* __restrict__ db1,
                const unsigned short* __restrict__ wD2, const float* __restrict__ db2,
                unsigned short* __restrict__ out)
{
    __shared__ __align__(16) unsigned short s_a[64][40];   // emb rows (bf16), pad->free
    __shared__ __align__(16) unsigned short s_f[64][40];   // feat rows
    __shared__ __align__(16) unsigned short s_x[64][136];  // activation [node][k], 272B row

    const int t = threadIdx.x;
    const int base = blockIdx.x * 64;

    // stage: 4 threads per node, 8 dims each; cvt f32->bf16, one b128 write
    {
        const int n = t >> 2, q = t & 3;
        const float* er = node_emb + ((size_t)(nid[base + n] + 1)) * 32 + q * 8;
        const float* fr = feat + ((size_t)(base + n)) * 32 + q * 8;
        short8 va, vf;
        #pragma unroll
        for (int i = 0; i < 8; ++i) { va[i] = (short)f2bf(er[i]); vf[i] = (short)f2bf(fr[i]); }
        *(short8*)&s_a[n][q * 8] = va;
        *(short8*)&s_f[n][q * 8] = vf;
    }
    __syncthreads();

    const int w = t >> 6, l = t & 63;
    const int lr = l & 15;            // A row / D col within tile
    const int lk = (l >> 4) * 8;      // k sub-chunk base
    const int rn0 = (l >> 4) * 4;     // D row base within tile

    // Phase A: h = lrelu(emb @ exp_W + exp_b), p = feat @ proj_W  (K=32, 1 kc)
    short8 aE = *(const short8*)&s_a[w * 16 + lr][lk];
    short8 aF = *(const short8*)&s_f[w * 16 + lr][lk];
    f32x4 acch[8], accp[8];
    const f32x4 zero = {0.f, 0.f, 0.f, 0.f};
    #pragma unroll
    for (int ft = 0; ft < 8; ++ft) {
        short8 bE = *(const short8*)&wExp[(ft * 64 + l) * 8];
        short8 bP = *(const short8*)&wProj[(ft * 64 + l) * 8];
        acch[ft] = __builtin_amdgcn_mfma_f32_16x16x32_bf16(aE, bE, zero, 0, 0, 0);
        accp[ft] = __builtin_amdgcn_mfma_f32_16x16x32_bf16(aF, bP, zero, 0, 0, 0);
    }

    // extra = emb_cat[cat] + lrelu(p + proj_b, 0.01) -> s_x (D-layout scatter)
    int cidx[4];
    #pragma unroll
    for (int r = 0; r < 4; ++r) cidx[r] = cat[base + w * 16 + rn0 + r];
    float pb[8], eb[8];
    #pragma unroll
    for (int ft = 0; ft < 8; ++ft) { pb[ft] = proj_b[ft * 16 + lr]; eb[ft] = exp_b[ft * 16 + lr]; }
    #pragma unroll
    for (int r = 0; r < 4; ++r) {
        const float* ecrow = emb_cat + (size_t)cidx[r] * 128;
        #pragma unroll
        for (int ft = 0; ft < 8; ++ft) {
            float ex = ecrow[ft * 16 + lr] + lrelu(accp[ft][r] + pb[ft], 0.01f);
            s_x[w * 16 + rn0 + r][ft * 16 + lr] = f2bf(ex);
            acch[ft][r] = lrelu(acch[ft][r] + eb[ft], 0.1f);
        }
    }
    __syncthreads();

    // Phase B: t1 = lrelu(extra @ dW1 + db1, 0.1)   (K=128, 4 kc)
    f32x4 acc[8];
    #pragma unroll
    for (int ft = 0; ft < 8; ++ft) acc[ft] = zero;
    #pragma unroll
    for (int kc = 0; kc < 4; ++kc) {
        short8 a = *(const short8*)&s_x[w * 16 + lr][kc * 32 + lk];
        #pragma unroll
        for (int ft = 0; ft < 8; ++ft) {
            short8 b = *(const short8*)&wD1[((kc * 8 + ft) * 64 + l) * 8];
            acc[ft] = __builtin_amdgcn_mfma_f32_16x16x32_bf16(a, b, acc[ft], 0, 0, 0);
        }
    }
    __syncthreads();
    #pragma unroll
    for (int ft = 0; ft < 8; ++ft)
        #pragma unroll
        for (int r = 0; r < 4; ++r)
            s_x[w * 16 + rn0 + r][ft * 16 + lr] = f2bf(lrelu(acc[ft][r] + db1[ft * 16 + lr], 0.1f));
    __syncthreads();

    // Phase C: mix = lrelu(t1 @ dW2 + db2, 0.1); out = h + mix
    #pragma unroll
    for (int ft = 0; ft < 8; ++ft) acc[ft] = zero;
    #pragma unroll
    for (int kc = 0; kc < 4; ++kc) {
        short8 a = *(const short8*)&s_x[w * 16 + lr][kc * 32 + lk];
        #pragma unroll
        for (int ft = 0; ft < 8; ++ft) {
            short8 b = *(const short8*)&wD2[((kc * 8 + ft) * 64 + l) * 8];
            acc[ft] = __builtin_amdgcn_mfma_f32_16x16x32_bf16(a, b, acc[ft], 0, 0, 0);
        }
    }
    __syncthreads();
    #pragma unroll
    for (int ft = 0; ft < 8; ++ft)
        #pragma unroll
        for (int r = 0; r < 4; ++r)
            s_x[w * 16 + rn0 + r][ft * 16 + lr] =
                f2bf(acch[ft][r] + lrelu(acc[ft][r] + db2[ft * 16 + lr], 0.1f));
    __syncthreads();

    // coalesced bf16 store: 4 threads/node x 32 dims (4x dwordx4 each)
    {
        const int n = t >> 2, q = t & 3;
        short8* dstv = (short8*)(out + (size_t)(base + n) * 128 + q * 32);
        #pragma unroll
        for (int i = 0; i < 4; ++i) dstv[i] = *(const short8*)&s_x[n][q * 32 + i * 8];
    }
}

// --- GraphSAGE conv block --------------------------------------------------
// mean over exactly 10 in-edges (dst=e/10), concat [self, mean] (K=256),
// W1 (256x128) + lrelu, W2 (128x128) + bias, then lrelu (b<2) or L2-norm (b=2).
__global__ __launch_bounds__(256, 4)
void conv_layer(const unsigned short* __restrict__ h_src,
                unsigned short* __restrict__ h_self,
                float* __restrict__ out_f32,
                const int* __restrict__ src,
                const unsigned short* __restrict__ wC1, const float* __restrict__ b1,
                const unsigned short* __restrict__ wC2, const float* __restrict__ b2,
                int do_norm)
{
    __shared__ __align__(16) unsigned short s_x[64][264];  // [node][k0..255], 528B row
    float* xf = (float*)s_x;                               // reuse as [64][132] f32

    const int t = threadIdx.x;
    const int base = blockIdx.x * 64;
    const int n = t >> 2, q = t & 3;

    // stage self (bf16 copy) + gather-mean (f32 accum) : 4 threads/node x 32 dims
    {
        const short8* selfp = (const short8*)(h_self + (size_t)(base + n) * 128 + q * 32);
        #pragma unroll
        for (int i = 0; i < 4; ++i) *(short8*)&s_x[n][q * 32 + i * 8] = selfp[i];

        float m[32];
        #pragma unroll
        for (int i = 0; i < 32; ++i) m[i] = 0.f;
        const int* sp = src + (size_t)(base + n) * 10;
        for (int e = 0; e < 10; ++e) {
            const short8* rp = (const short8*)(h_src + (size_t)sp[e] * 128 + q * 32);
            #pragma unroll
            for (int i = 0; i < 4; ++i) {
                short8 v = rp[i];
                #pragma unroll
                for (int j = 0; j < 8; ++j) m[i * 8 + j] += bf2f((unsigned short)v[j]);
            }
        }
        #pragma unroll
        for (int i = 0; i < 4; ++i) {
            short8 pm;
            #pragma unroll
            for (int j = 0; j < 8; ++j) pm[j] = (short)f2bf(m[i * 8 + j] * 0.1f);
            *(short8*)&s_x[n][128 + q * 32 + i * 8] = pm;
        }
    }
    __syncthreads();

    const int w = t >> 6, l = t & 63;
    const int lr = l & 15, lk = (l >> 4) * 8, rn0 = (l >> 4) * 4;
    const f32x4 zero = {0.f, 0.f, 0.f, 0.f};

    // W1: K=256 -> 8 kc
    f32x4 acc[8];
    #pragma unroll
    for (int ft = 0; ft < 8; ++ft) acc[ft] = zero;
    #pragma unroll
    for (int kc = 0; kc < 8; ++kc) {
        short8 a = *(const short8*)&s_x[w * 16 + lr][kc * 32 + lk];
        #pragma unroll
        for (int ft = 0; ft < 8; ++ft) {
            short8 b = *(const short8*)&wC1[((kc * 8 + ft) * 64 + l) * 8];
            acc[ft] = __builtin_amdgcn_mfma_f32_16x16x32_bf16(a, b, acc[ft], 0, 0, 0);
        }
    }
    __syncthreads();
    #pragma unroll
    for (int ft = 0; ft < 8; ++ft)
        #pragma unroll
        for (int r = 0; r < 4; ++r)
            s_x[w * 16 + rn0 + r][ft * 16 + lr] = f2bf(lrelu(acc[ft][r] + b1[ft * 16 + lr], 0.1f));
    __syncthreads();

    // W2: K=128 -> 4 kc
    f32x4 acc2[8];
    #pragma unroll
    for (int ft = 0; ft < 8; ++ft) acc2[ft] = zero;
    #pragma unroll
    for (int kc = 0; kc < 4; ++kc) {
        short8 a = *(const short8*)&s_x[w * 16 + lr][kc * 32 + lk];
        #pragma unroll
        for (int ft = 0; ft < 8; ++ft) {
            short8 b = *(const short8*)&wC2[((kc * 8 + ft) * 64 + l) * 8];
            acc2[ft] = __builtin_amdgcn_mfma_f32_16x16x32_bf16(a, b, acc2[ft], 0, 0, 0);
        }
    }
    __syncthreads();

    if (!do_norm) {
        #pragma unroll
        for (int ft = 0; ft < 8; ++ft)
            #pragma unroll
            for (int r = 0; r < 4; ++r)
                s_x[w * 16 + rn0 + r][ft * 16 + lr] =
                    f2bf(lrelu(acc2[ft][r] + b2[ft * 16 + lr], 0.1f));
        __syncthreads();
        short8* dstv = (short8*)(h_self + (size_t)(base + n) * 128 + q * 32);
        #pragma unroll
        for (int i = 0; i < 4; ++i) dstv[i] = *(const short8*)&s_x[n][q * 32 + i * 8];
    } else {
        // stage hn (f32) then per-node L2-normalize; write f32 output
        #pragma unroll
        for (int ft = 0; ft < 8; ++ft)
            #pragma unroll
            for (int r = 0; r < 4; ++r)
                xf[(w * 16 + rn0 + r) * 132 + ft * 16 + lr] = acc2[ft][r] + b2[ft * 16 + lr];
        __syncthreads();
        f32x4 v[8];
        float ss = 0.f;
        #pragma unroll
        for (int c = 0; c < 8; ++c) {
            v[c] = *(const f32x4*)&xf[n * 132 + q * 32 + c * 4];
            ss += v[c][0] * v[c][0] + v[c][1] * v[c][1] + v[c][2] * v[c][2] + v[c][3] * v[c][3];
        }
        ss += __shfl_xor(ss, 1);
        ss += __shfl_xor(ss, 2);
        const float sc = 1.0f / fmaxf(sqrtf(ss), 1e-6f);
        float* op = out_f32 + (size_t)(base + n) * 128 + q * 32;
        #pragma unroll
        for (int c = 0; c < 8; ++c) {
            f32x4 o = {v[c][0] * sc, v[c][1] * sc, v[c][2] * sc, v[c][3] * sc};
            *(f32x4*)&op[c * 4] = o;
        }
    }
}

extern "C" void kernel_launch(void* const* d_in, const int* in_sizes, int n_in,
                              void* d_out, int out_size, void* d_ws, size_t ws_size,
                              hipStream_t stream)
{
    const int* nid[4]  = {(const int*)d_in[0], (const int*)d_in[3], (const int*)d_in[6], (const int*)d_in[9]};
    const int* cat[4]  = {(const int*)d_in[1], (const int*)d_in[4], (const int*)d_in[7], (const int*)d_in[10]};
    const float* feat[4] = {(const float*)d_in[2], (const float*)d_in[5], (const float*)d_in[8], (const float*)d_in[11]};
    const int* src[3]  = {(const int*)d_in[12], (const int*)d_in[14], (const int*)d_in[16]};
    const float* node_emb = (const float*)d_in[18];
    const float* exp_W  = (const float*)d_in[19];
    const float* exp_b  = (const float*)d_in[20];
    const float* emb_cat = (const float*)d_in[21];
    const float* proj_W = (const float*)d_in[22];
    const float* proj_b = (const float*)d_in[23];
    const float* dW1    = (const float*)d_in[24];
    const float* db1    = (const float*)d_in[25];
    const float* dW2    = (const float*)d_in[26];
    const float* db2    = (const float*)d_in[27];
    const float* cW1    = (const float*)d_in[28];
    const float* cb1    = (const float*)d_in[29];
    const float* cW2    = (const float*)d_in[30];
    const float* cb2    = (const float*)d_in[31];

    const int L[4] = {524288, 131072, 32768, 8192};
    unsigned short* hs[4];
    hs[0] = (unsigned short*)d_ws;
    hs[1] = hs[0] + (size_t)L[0] * 128;
    hs[2] = hs[1] + (size_t)L[1] * 128;
    hs[3] = hs[2] + (size_t)L[2] * 128;
    unsigned short* wfrag = hs[3] + (size_t)L[3] * 128;

    prep_weights<<<(W_TOTAL + 255) / 256, 256, 0, stream>>>(
        exp_W, proj_W, dW1, dW2, cW1, cW2, wfrag);

    for (int i = 0; i < 4; ++i) {
        init_layer<<<L[i] / 64, 256, 0, stream>>>(
            nid[i], cat[i], feat[i], node_emb,
            wfrag + W_EXP, exp_b, emb_cat,
            wfrag + W_PROJ, proj_b,
            wfrag + W_D1, db1, wfrag + W_D2, db2, hs[i]);
    }
    for (int b = 0; b < 3; ++b) {
        conv_layer<<<L[b + 1] / 64, 256, 0, stream>>>(
            hs[b], hs[b + 1], (b == 2) ? (float*)d_out : nullptr, src[b],
            wfrag + W_C1 + b * 32768, cb1 + (size_t)b * 128,
            wfrag + W_C2 + b * 16384, cb2 + (size_t)b * 128,
            (b == 2) ? 1 : 0);
    }
}

// Round 4
// 630.782 us; speedup vs baseline: 2.6063x; 1.1667x over previous
//
#include <hip/hip_runtime.h>

// ---------------------------------------------------------------------------
// GraphSAGE forward, bf16-MFMA, occupancy-optimized.
// MFMA 16x16x32 bf16 layout (gfx950):
//   A: lane l holds A[l&15][(l>>4)*8 + j]; B: lane l holds B[(l>>4)*8+j][l&15]
//   C/D: lane l, reg r holds D[(l>>4)*4 + r][l&15]   (verified m89/m91)
// 512-thread blocks, 64 nodes/block; wave w owns (row-tile w>>1, ft-half w&1).
// ---------------------------------------------------------------------------

typedef __attribute__((ext_vector_type(8))) short short8;
typedef __attribute__((ext_vector_type(4))) float f32x4;

__device__ __forceinline__ float lrelu(float x, float s) { return x >= 0.0f ? x : s * x; }
__device__ __forceinline__ unsigned short f2bf(float x) {
    unsigned u = __float_as_uint(x);
    return (unsigned short)((u + 0x7FFFu + ((u >> 16) & 1u)) >> 16);
}
__device__ __forceinline__ float bf2f(unsigned short u) {
    return __uint_as_float(((unsigned)u) << 16);
}

// weight fragment arena offsets (ushort elements)
#define W_EXP   0
#define W_PROJ  4096
#define W_D1    8192
#define W_D2    24576
#define W_C1    40960      // + b*32768
#define W_C2    139264     // + b*16384
#define W_EC    188416     // emb_cat bf16 copy (1000*128)
#define W_TOTAL 316416

__global__ __launch_bounds__(256)
void prep_weights(const float* __restrict__ expW, const float* __restrict__ projW,
                  const float* __restrict__ dW1, const float* __restrict__ dW2,
                  const float* __restrict__ cW1, const float* __restrict__ cW2,
                  const float* __restrict__ embcat,
                  unsigned short* __restrict__ dst)
{
    int gid = blockIdx.x * 256 + threadIdx.x;
    if (gid >= W_TOTAL) return;
    if (gid >= W_EC) { int e = gid - W_EC; dst[W_EC + e] = f2bf(embcat[e]); return; }
    const float* src; int e, dbase;
    if (gid < W_PROJ)      { src = expW;  e = gid;          dbase = W_EXP; }
    else if (gid < W_D1)   { src = projW; e = gid - W_PROJ; dbase = W_PROJ; }
    else if (gid < W_D2)   { src = dW1;   e = gid - W_D1;   dbase = W_D1; }
    else if (gid < W_C1)   { src = dW2;   e = gid - W_D2;   dbase = W_D2; }
    else if (gid < W_C2)   { int r = gid - W_C1; int b = r / 32768; int w2 = r % 32768;
                             src = cW1 + (size_t)b * 32768; e = w2; dbase = W_C1 + b * 32768; }
    else                   { int r = gid - W_C2; int b = r / 16384; int w2 = r % 16384;
                             src = cW2 + (size_t)b * 16384; e = w2; dbase = W_C2 + b * 16384; }
    int k = e >> 7, f = e & 127;
    int kc = k >> 5, kr = k & 31, ft = f >> 4;
    int lane = ((kr >> 3) << 4) | (f & 15);
    int j = kr & 7;
    dst[dbase + ((kc * 8 + ft) * 64 + lane) * 8 + j] = f2bf(src[e]);
}

struct GArgs {
    const int* nid[4];
    const int* cat[4];
    const float* feat[4];
    unsigned short* out[4];
};

// All 4 init layers in one grid. 64 nodes/block, 512 threads (8 waves).
__global__ __launch_bounds__(512, 6)
void init_all(GArgs P, const float* __restrict__ node_emb,
              const unsigned short* __restrict__ wExp, const float* __restrict__ exp_b,
              const unsigned short* __restrict__ ecb,
              const unsigned short* __restrict__ wProj, const float* __restrict__ proj_b,
              const unsigned short* __restrict__ wD1, const float* __restrict__ db1,
              const unsigned short* __restrict__ wD2, const float* __restrict__ db2)
{
    __shared__ __align__(16) unsigned short s_x[64][136];  // [node][k], 272B row

    int bk = blockIdx.x, layer, lb;
    if (bk < 8192)       { layer = 0; lb = bk; }
    else if (bk < 10240) { layer = 1; lb = bk - 8192; }
    else if (bk < 10752) { layer = 2; lb = bk - 10240; }
    else                 { layer = 3; lb = bk - 10752; }
    const int* __restrict__ nid = P.nid[layer];
    const int* __restrict__ cat = P.cat[layer];
    const float* __restrict__ feat = P.feat[layer];
    unsigned short* __restrict__ out = P.out[layer];
    const int base = lb * 64;

    const int t = threadIdx.x;
    const int w = t >> 6, l = t & 63;
    const int rt = w >> 1;            // row tile (16 nodes)
    const int fh = (w & 1) * 4;       // ft base (4 of 8 tiles)
    const int lr = l & 15, lk = (l >> 4) * 8, rn0 = (l >> 4) * 4;
    const int nrow = rt * 16 + lr;
    const f32x4 zero = {0.f, 0.f, 0.f, 0.f};

    // A fragments direct from global (no LDS staging)
    const float* er = node_emb + (size_t)(nid[base + nrow] + 1) * 32 + lk;
    const float* fr = feat + (size_t)(base + nrow) * 32 + lk;
    short8 aE, aF;
    #pragma unroll
    for (int i = 0; i < 8; ++i) { aE[i] = (short)f2bf(er[i]); aF[i] = (short)f2bf(fr[i]); }

    // Phase A: h = emb @ exp_W, p = feat @ proj_W (K=32), this wave's 4 ft tiles
    f32x4 acch[4], accp[4];
    #pragma unroll
    for (int ftl = 0; ftl < 4; ++ftl) {
        short8 bE = *(const short8*)&wExp[((fh + ftl) * 64 + l) * 8];
        short8 bP = *(const short8*)&wProj[((fh + ftl) * 64 + l) * 8];
        acch[ftl] = __builtin_amdgcn_mfma_f32_16x16x32_bf16(aE, bE, zero, 0, 0, 0);
        accp[ftl] = __builtin_amdgcn_mfma_f32_16x16x32_bf16(aF, bP, zero, 0, 0, 0);
    }

    int cidx[4];
    #pragma unroll
    for (int r = 0; r < 4; ++r) cidx[r] = cat[base + rt * 16 + rn0 + r];

    // extra = emb_cat[cat] + lrelu(p + proj_b, 0.01) -> s_x (D-layout)
    #pragma unroll
    for (int ftl = 0; ftl < 4; ++ftl) {
        const int col = (fh + ftl) * 16 + lr;
        const float pb = proj_b[col];
        #pragma unroll
        for (int r = 0; r < 4; ++r) {
            float ex = bf2f(ecb[(size_t)cidx[r] * 128 + col]) + lrelu(accp[ftl][r] + pb, 0.01f);
            s_x[rt * 16 + rn0 + r][col] = f2bf(ex);
        }
    }
    // park lrelu(h) as packed bf16 (8 VGPRs)
    unsigned hp[8];
    #pragma unroll
    for (int ftl = 0; ftl < 4; ++ftl) {
        const float eb = exp_b[(fh + ftl) * 16 + lr];
        #pragma unroll
        for (int rp = 0; rp < 2; ++rp) {
            unsigned lo = f2bf(lrelu(acch[ftl][rp * 2 + 0] + eb, 0.1f));
            unsigned hi = f2bf(lrelu(acch[ftl][rp * 2 + 1] + eb, 0.1f));
            hp[ftl * 2 + rp] = lo | (hi << 16);
        }
    }
    __syncthreads();

    // Phase B: t1 = lrelu(extra @ dW1 + db1, 0.1)   (K=128)
    f32x4 acc[4];
    #pragma unroll
    for (int ftl = 0; ftl < 4; ++ftl) acc[ftl] = zero;
    #pragma unroll
    for (int kc = 0; kc < 4; ++kc) {
        short8 a = *(const short8*)&s_x[rt * 16 + lr][kc * 32 + lk];
        #pragma unroll
        for (int ftl = 0; ftl < 4; ++ftl) {
            short8 b = *(const short8*)&wD1[((kc * 8 + fh + ftl) * 64 + l) * 8];
            acc[ftl] = __builtin_amdgcn_mfma_f32_16x16x32_bf16(a, b, acc[ftl], 0, 0, 0);
        }
    }
    __syncthreads();
    #pragma unroll
    for (int ftl = 0; ftl < 4; ++ftl) {
        const int col = (fh + ftl) * 16 + lr;
        const float bb = db1[col];
        #pragma unroll
        for (int r = 0; r < 4; ++r)
            s_x[rt * 16 + rn0 + r][col] = f2bf(lrelu(acc[ftl][r] + bb, 0.1f));
    }
    __syncthreads();

    // Phase C: mix = lrelu(t1 @ dW2 + db2, 0.1); out = h + mix
    f32x4 acc2[4];
    #pragma unroll
    for (int ftl = 0; ftl < 4; ++ftl) acc2[ftl] = zero;
    #pragma unroll
    for (int kc = 0; kc < 4; ++kc) {
        short8 a = *(const short8*)&s_x[rt * 16 + lr][kc * 32 + lk];
        #pragma unroll
        for (int ftl = 0; ftl < 4; ++ftl) {
            short8 b = *(const short8*)&wD2[((kc * 8 + fh + ftl) * 64 + l) * 8];
            acc2[ftl] = __builtin_amdgcn_mfma_f32_16x16x32_bf16(a, b, acc2[ftl], 0, 0, 0);
        }
    }
    __syncthreads();
    #pragma unroll
    for (int ftl = 0; ftl < 4; ++ftl) {
        const int col = (fh + ftl) * 16 + lr;
        const float bb = db2[col];
        #pragma unroll
        for (int rp = 0; rp < 2; ++rp) {
            float h0 = bf2f((unsigned short)(hp[ftl * 2 + rp] & 0xffffu));
            float h1 = bf2f((unsigned short)(hp[ftl * 2 + rp] >> 16));
            s_x[rt * 16 + rn0 + rp * 2 + 0][col] = f2bf(h0 + lrelu(acc2[ftl][rp * 2 + 0] + bb, 0.1f));
            s_x[rt * 16 + rn0 + rp * 2 + 1][col] = f2bf(h1 + lrelu(acc2[ftl][rp * 2 + 1] + bb, 0.1f));
        }
    }
    __syncthreads();

    // coalesced store: 512 threads x 32B
    {
        const int n = t >> 3, q2 = t & 7;
        short8* dstv = (short8*)(out + (size_t)(base + n) * 128 + q2 * 16);
        dstv[0] = *(const short8*)&s_x[n][q2 * 16];
        dstv[1] = *(const short8*)&s_x[n][q2 * 16 + 8];
    }
}

// GraphSAGE conv block: 64 dst nodes/block, 512 threads.
__global__ __launch_bounds__(512, 6)
void conv_layer(const unsigned short* __restrict__ h_src,
                unsigned short* __restrict__ h_self,
                float* __restrict__ out_f32,
                const int* __restrict__ src,
                const unsigned short* __restrict__ wC1, const float* __restrict__ b1,
                const unsigned short* __restrict__ wC2, const float* __restrict__ b2,
                int do_norm)
{
    __shared__ __align__(16) unsigned short s_x[64][264];  // [node][k0..255]
    float* xf = (float*)s_x;                               // reuse [64][132] f32

    const int t = threadIdx.x;
    const int base = blockIdx.x * 64;

    // stage self + gather-mean: 8 threads/node, 16 dims each
    {
        const int n = t >> 3, q2 = t & 7;
        const int d0 = q2 * 16;
        const short8* selfp = (const short8*)(h_self + (size_t)(base + n) * 128 + d0);
        short8 s0 = selfp[0], s1 = selfp[1];
        *(short8*)&s_x[n][d0] = s0;
        *(short8*)&s_x[n][d0 + 8] = s1;

        int si[10];
        const int* sp = src + (size_t)(base + n) * 10;
        #pragma unroll
        for (int e = 0; e < 10; ++e) si[e] = sp[e];
        float m[16];
        #pragma unroll
        for (int i = 0; i < 16; ++i) m[i] = 0.f;
        #pragma unroll
        for (int e = 0; e < 10; ++e) {
            const short8* rp = (const short8*)(h_src + (size_t)si[e] * 128 + d0);
            short8 v0 = rp[0], v1 = rp[1];
            #pragma unroll
            for (int j = 0; j < 8; ++j) {
                m[j]     += bf2f((unsigned short)v0[j]);
                m[8 + j] += bf2f((unsigned short)v1[j]);
            }
        }
        short8 p0, p1;
        #pragma unroll
        for (int j = 0; j < 8; ++j) {
            p0[j] = (short)f2bf(m[j] * 0.1f);
            p1[j] = (short)f2bf(m[8 + j] * 0.1f);
        }
        *(short8*)&s_x[n][128 + d0] = p0;
        *(short8*)&s_x[n][128 + d0 + 8] = p1;
    }
    __syncthreads();

    const int w = t >> 6, l = t & 63;
    const int rt = w >> 1, fh = (w & 1) * 4;
    const int lr = l & 15, lk = (l >> 4) * 8, rn0 = (l >> 4) * 4;
    const f32x4 zero = {0.f, 0.f, 0.f, 0.f};

    // W1: K=256
    f32x4 acc[4];
    #pragma unroll
    for (int ftl = 0; ftl < 4; ++ftl) acc[ftl] = zero;
    #pragma unroll
    for (int kc = 0; kc < 8; ++kc) {
        short8 a = *(const short8*)&s_x[rt * 16 + lr][kc * 32 + lk];
        #pragma unroll
        for (int ftl = 0; ftl < 4; ++ftl) {
            short8 b = *(const short8*)&wC1[((kc * 8 + fh + ftl) * 64 + l) * 8];
            acc[ftl] = __builtin_amdgcn_mfma_f32_16x16x32_bf16(a, b, acc[ftl], 0, 0, 0);
        }
    }
    __syncthreads();
    #pragma unroll
    for (int ftl = 0; ftl < 4; ++ftl) {
        const int col = (fh + ftl) * 16 + lr;
        const float bb = b1[col];
        #pragma unroll
        for (int r = 0; r < 4; ++r)
            s_x[rt * 16 + rn0 + r][col] = f2bf(lrelu(acc[ftl][r] + bb, 0.1f));
    }
    __syncthreads();

    // W2: K=128
    f32x4 acc2[4];
    #pragma unroll
    for (int ftl = 0; ftl < 4; ++ftl) acc2[ftl] = zero;
    #pragma unroll
    for (int kc = 0; kc < 4; ++kc) {
        short8 a = *(const short8*)&s_x[rt * 16 + lr][kc * 32 + lk];
        #pragma unroll
        for (int ftl = 0; ftl < 4; ++ftl) {
            short8 b = *(const short8*)&wC2[((kc * 8 + fh + ftl) * 64 + l) * 8];
            acc2[ftl] = __builtin_amdgcn_mfma_f32_16x16x32_bf16(a, b, acc2[ftl], 0, 0, 0);
        }
    }
    __syncthreads();

    if (!do_norm) {
        #pragma unroll
        for (int ftl = 0; ftl < 4; ++ftl) {
            const int col = (fh + ftl) * 16 + lr;
            const float bb = b2[col];
            #pragma unroll
            for (int r = 0; r < 4; ++r)
                s_x[rt * 16 + rn0 + r][col] = f2bf(lrelu(acc2[ftl][r] + bb, 0.1f));
        }
        __syncthreads();
        const int n = t >> 3, q2 = t & 7;
        short8* dstv = (short8*)(h_self + (size_t)(base + n) * 128 + q2 * 16);
        dstv[0] = *(const short8*)&s_x[n][q2 * 16];
        dstv[1] = *(const short8*)&s_x[n][q2 * 16 + 8];
    } else {
        #pragma unroll
        for (int ftl = 0; ftl < 4; ++ftl) {
            const int col = (fh + ftl) * 16 + lr;
            const float bb = b2[col];
            #pragma unroll
            for (int r = 0; r < 4; ++r)
                xf[(rt * 16 + rn0 + r) * 132 + col] = acc2[ftl][r] + bb;
        }
        __syncthreads();
        const int n = t >> 3, q2 = t & 7;
        f32x4 v[4];
        float ss = 0.f;
        #pragma unroll
        for (int c = 0; c < 4; ++c) {
            v[c] = *(const f32x4*)&xf[n * 132 + q2 * 16 + c * 4];
            ss += v[c][0] * v[c][0] + v[c][1] * v[c][1] + v[c][2] * v[c][2] + v[c][3] * v[c][3];
        }
        ss += __shfl_xor(ss, 1);
        ss += __shfl_xor(ss, 2);
        ss += __shfl_xor(ss, 4);
        const float sc = 1.0f / fmaxf(sqrtf(ss), 1e-6f);
        float* op = out_f32 + (size_t)(base + n) * 128 + q2 * 16;
        #pragma unroll
        for (int c = 0; c < 4; ++c) {
            f32x4 o = {v[c][0] * sc, v[c][1] * sc, v[c][2] * sc, v[c][3] * sc};
            *(f32x4*)&op[c * 4] = o;
        }
    }
}

extern "C" void kernel_launch(void* const* d_in, const int* in_sizes, int n_in,
                              void* d_out, int out_size, void* d_ws, size_t ws_size,
                              hipStream_t stream)
{
    const float* node_emb = (const float*)d_in[18];
    const float* exp_W  = (const float*)d_in[19];
    const float* exp_b  = (const float*)d_in[20];
    const float* emb_cat = (const float*)d_in[21];
    const float* proj_W = (const float*)d_in[22];
    const float* proj_b = (const float*)d_in[23];
    const float* dW1    = (const float*)d_in[24];
    const float* db1    = (const float*)d_in[25];
    const float* dW2    = (const float*)d_in[26];
    const float* db2    = (const float*)d_in[27];
    const float* cW1    = (const float*)d_in[28];
    const float* cb1    = (const float*)d_in[29];
    const float* cW2    = (const float*)d_in[30];
    const float* cb2    = (const float*)d_in[31];

    const int L[4] = {524288, 131072, 32768, 8192};
    unsigned short* hs[4];
    hs[0] = (unsigned short*)d_ws;
    hs[1] = hs[0] + (size_t)L[0] * 128;
    hs[2] = hs[1] + (size_t)L[1] * 128;
    hs[3] = hs[2] + (size_t)L[2] * 128;
    unsigned short* wf = hs[3] + (size_t)L[3] * 128;

    prep_weights<<<(W_TOTAL + 255) / 256, 256, 0, stream>>>(
        exp_W, proj_W, dW1, dW2, cW1, cW2, emb_cat, wf);

    GArgs P;
    P.nid[0] = (const int*)d_in[0]; P.nid[1] = (const int*)d_in[3];
    P.nid[2] = (const int*)d_in[6]; P.nid[3] = (const int*)d_in[9];
    P.cat[0] = (const int*)d_in[1]; P.cat[1] = (const int*)d_in[4];
    P.cat[2] = (const int*)d_in[7]; P.cat[3] = (const int*)d_in[10];
    P.feat[0] = (const float*)d_in[2]; P.feat[1] = (const float*)d_in[5];
    P.feat[2] = (const float*)d_in[8]; P.feat[3] = (const float*)d_in[11];
    P.out[0] = hs[0]; P.out[1] = hs[1]; P.out[2] = hs[2]; P.out[3] = hs[3];

    init_all<<<10880, 512, 0, stream>>>(
        P, node_emb, wf + W_EXP, exp_b, wf + W_EC,
        wf + W_PROJ, proj_b, wf + W_D1, db1, wf + W_D2, db2);

    const int* src[3] = {(const int*)d_in[12], (const int*)d_in[14], (const int*)d_in[16]};
    for (int b = 0; b < 3; ++b) {
        conv_layer<<<L[b + 1] / 64, 512, 0, stream>>>(
            hs[b], hs[b + 1], (b == 2) ? (float*)d_out : nullptr, src[b],
            wf + W_C1 + b * 32768, cb1 + (size_t)b * 128,
            wf + W_C2 + b * 16384, cb2 + (size_t)b * 128,
            (b == 2) ? 1 : 0);
    }
}